// Round 8
// baseline (584.909 us; speedup 1.0000x reference)
//
#include <hip/hip_runtime.h>
#include <hip/hip_cooperative_groups.h>
#include <math.h>

namespace cg = cooperative_groups;

// ---------------------------------------------------------------------------
// NFFT forward (type-2), single cooperative kernel (3 phases, 2 grid syncs):
//   A: fused deconvolve/pad/fftshift + 512-pt row FFT (256 nonzero rows/img)
//   B: 512-pt col FFT (zeros injected for never-written middle rows)
//   C: coalesced gather, 8 lanes per (img,point), grid-stride
// Fallback (any cooperative-launch error): round-7 proven 3-dispatch path.
// Shift algebra: ifftshift(FFT(fftshift(p)))[(ind+256)%512] == FFT(fftshift(p))[ind&511].
// Output PLANAR: real plane (B,C,M) then imag plane.
// R4 lesson: no forced __launch_bounds__ minima (spill -> dead kernel).
// R5 lesson: scattered per-lane gather is L1-transaction bound -> coalesce.
// R7 lesson: ~10-15us per dispatch boundary in this harness -> fuse dispatches.
// ---------------------------------------------------------------------------

#define NGRID 512
#define NSMALL 256
#define MW 4
#define BB 2
#define CC 2
#define MPTS 200000
#define PLANE (BB * CC * MPTS)   // imag-plane offset in floats
#define COOP_BLOCKS 2048         // 8 blocks/CU on 256 CUs (LDS 4KB, VGPR small)

// I0(z) asymptotic series, valid z > 8 (our z in [17.7, 18.9])
__device__ __forceinline__ float nfft29781_i0_large(float z) {
    float inv = 1.0f / z;
    float p = 1.0f + inv * (0.125f + inv * (0.0703125f
              + inv * (0.0732421875f + inv * 0.112152099609375f)));
    return expf(z) * rsqrtf(2.0f * (float)M_PI * z) * p;
}

__device__ __forceinline__ int nfft29781_brev9(int v) {
    return (int)(__brev((unsigned)v) >> 23);
}

// 512-pt radix-2 DIT FFT in LDS (input pre-loaded bit-reversed).
__device__ __forceinline__ void nfft29781_fft512(float2* s, int tid) {
    #pragma unroll
    for (int st = 0; st < 9; ++st) {
        int half = 1 << st;
        int pos = tid & (half - 1);
        int i0 = ((tid >> st) << (st + 1)) + pos;
        int i1 = i0 + half;
        float ang = -(float)M_PI * (float)pos / (float)half;
        float sn, cs;
        __sincosf(ang, &sn, &cs);
        float2 a = s[i0];
        float2 b = s[i1];
        float2 tw = make_float2(b.x * cs - b.y * sn, b.x * sn + b.y * cs);
        s[i0] = make_float2(a.x + tw.x, a.y + tw.y);
        s[i1] = make_float2(a.x - tw.x, a.y - tw.y);
        __syncthreads();
    }
}

// --------------------------- phase bodies (shared) -------------------------

__device__ __forceinline__ void nfft29781_rows_body(const float* __restrict__ fr,
                                                    const float* __restrict__ fi,
                                                    float2* __restrict__ G,
                                                    float2* s, int blk, int tid) {
    int img = blk >> 8;
    int a1  = blk & 255;

    const float bcon  = 1.5f * (float)M_PI;
    const float scale = 2.0f * (float)M_PI / (float)NGRID;
    float k1 = (float)(a1 - 128) * scale;
    float p1 = nfft29781_i0_large((float)MW * sqrtf(bcon * bcon - k1 * k1));

    int a2 = tid ^ 128;
    float k2 = (float)(a2 - 128) * scale;
    float p2 = nfft29781_i0_large((float)MW * sqrtf(bcon * bcon - k2 * k2));

    size_t src = ((size_t)img * NSMALL + a1) * NSMALL + a2;
    float invp = 1.0f / (p1 * p2);
    float2 v = make_float2(fr[src] * invp, fi[src] * invp);

    int j2v = (tid < 128) ? tid : tid + 256;        // nonzero staged col
    int j2z = (tid < 128) ? tid + 256 : tid;        // zero staged col
    s[nfft29781_brev9(j2v)] = v;
    s[nfft29781_brev9(j2z)] = make_float2(0.0f, 0.0f);
    __syncthreads();

    nfft29781_fft512(s, tid);

    int j1 = (a1 < 128) ? a1 + 384 : a1 - 128;      // staged row (fftshift fold)
    size_t base = ((size_t)img * NGRID + j1) * NGRID;
    G[base + tid]       = s[tid];
    G[base + tid + 256] = s[tid + 256];
}

__device__ __forceinline__ void nfft29781_cols_body(float2* __restrict__ G,
                                                    float2* s, int blk, int tid) {
    int col = blk & (NGRID - 1);
    int img = blk >> 9;
    size_t base = (size_t)img * NGRID * NGRID + col;

    int r0 = tid, r1 = tid + 256;
    float2 v0 = (r0 >= 128) ? make_float2(0.0f, 0.0f) : G[base + (size_t)r0 * NGRID];
    float2 v1 = (r1 <  384) ? make_float2(0.0f, 0.0f) : G[base + (size_t)r1 * NGRID];
    s[nfft29781_brev9(r0)] = v0;
    s[nfft29781_brev9(r1)] = v1;
    __syncthreads();

    nfft29781_fft512(s, tid);

    G[base + (size_t)r0 * NGRID] = s[r0];
    G[base + (size_t)r1 * NGRID] = s[r1];
}

__device__ __forceinline__ void nfft29781_gather_body(const float* __restrict__ x,
                                                      const float2* __restrict__ G,
                                                      float* __restrict__ out,
                                                      int out_elems, int t, int lane) {
    int j  = t & 7;                  // my column tap
    int pp = t >> 3;                 // (img, point) id — all 8 group lanes share
    int img = pp / MPTS;             // b*CC + c
    int pt  = pp - img * MPTS;
    int b   = img >> 1;              // CC == 2

    size_t xi = (size_t)(b * MPTS + pt) * 2;
    float u0 = x[xi + 0] * (float)NGRID;   // 8 lanes same addr -> broadcast
    float u1 = x[xi + 1] * (float)NGRID;

    float c0 = ceilf(u0), c1 = ceilf(u1);
    int base0 = (int)c0 - MW;
    int base1 = (int)c1 - MW;
    float d0 = c0 - u0, d1 = c1 - u1;

    const float bw = 1.5f * (float)M_PI;
    const float invpi = 1.0f / (float)M_PI;
    float w0m, w1m;
    {
        float nk = (float)(MW - j) - d0;
        float tt = (float)(MW * MW) - nk * nk;
        w0m = 0.0f;
        if (tt > 0.0f) { float a = sqrtf(tt); float e = expf(bw * a);
                         w0m = (e - 1.0f / e) * 0.5f * invpi / a; }
        nk = (float)(MW - j) - d1;
        tt = (float)(MW * MW) - nk * nk;
        w1m = 0.0f;
        if (tt > 0.0f) { float a = sqrtf(tt); float e = expf(bw * a);
                         w1m = (e - 1.0f / e) * 0.5f * invpi / a; }
    }

    const float2* Gi = G + (size_t)img * NGRID * NGRID;
    int cix = (base1 + j) & (NGRID - 1);
    int lanebase = lane & ~7;                 // my group's base lane

    float accx = 0.0f, accy = 0.0f;
    #pragma unroll
    for (int i = 0; i < 8; ++i) {
        float w0i = __shfl(w0m, lanebase + i, 64);   // row-i weight
        int row = (base0 + i) & (NGRID - 1);
        float2 g = Gi[(row << 9) + cix];
        accx += w0i * g.x;
        accy += w0i * g.y;
    }
    accx *= w1m;
    accy *= w1m;

    #pragma unroll
    for (int msk = 1; msk < 8; msk <<= 1) {    // sum over the 8 column taps
        accx += __shfl_xor(accx, msk, 64);
        accy += __shfl_xor(accy, msk, 64);
    }

    if (j == 0) {
        size_t o = (size_t)pp;                 // img*MPTS + pt
        if (o < (size_t)out_elems)         out[o]         = accx;
        if (PLANE + o < (size_t)out_elems) out[PLANE + o] = accy;
    }
}

// --------------------------- fused cooperative kernel ----------------------

__global__ __launch_bounds__(256) void nfft29781_fused(const float* __restrict__ x,
                                                       const float* __restrict__ fr,
                                                       const float* __restrict__ fi,
                                                       float2* __restrict__ G,
                                                       float* __restrict__ out,
                                                       int out_elems) {
    cg::grid_group grid = cg::this_grid();
    __shared__ float2 s[NGRID];
    int tid = threadIdx.x;
    int blk = blockIdx.x;

    // Phase A: 1024 row-FFT units on blocks 0..1023
    if (blk < BB * CC * NSMALL)
        nfft29781_rows_body(fr, fi, G, s, blk, tid);
    grid.sync();

    // Phase B: 2048 col-FFT units, one per block
    nfft29781_cols_body(G, s, blk, tid);
    grid.sync();

    // Phase C: gather, grid-stride (stride multiple of 64 keeps groups intact)
    int lane = tid & 63;
    int total  = BB * CC * MPTS * 8;          // 6,400,000 (multiple of 64)
    int stride = (int)(gridDim.x * blockDim.x);
    for (int t = blk * 256 + tid; t < total; t += stride)
        nfft29781_gather_body(x, G, out, out_elems, t, lane);
}

// --------------------------- fallback kernels (round-7 verbatim) -----------

__global__ __launch_bounds__(256) void nfft29781_rows_fused(const float* __restrict__ fr,
                                                            const float* __restrict__ fi,
                                                            float2* __restrict__ G) {
    __shared__ float2 s[NGRID];
    nfft29781_rows_body(fr, fi, G, s, blockIdx.x, threadIdx.x);
}

__global__ __launch_bounds__(256) void nfft29781_cols(float2* __restrict__ G) {
    __shared__ float2 s[NGRID];
    nfft29781_cols_body(G, s, blockIdx.x, threadIdx.x);
}

__global__ __launch_bounds__(256) void nfft29781_gather_coal(const float* __restrict__ x,
                                                             const float2* __restrict__ G,
                                                             float* __restrict__ out,
                                                             int out_elems) {
    int t = blockIdx.x * blockDim.x + threadIdx.x;
    if ((t >> 3) >= BB * CC * MPTS) return;
    nfft29781_gather_body(x, G, out, out_elems, t, threadIdx.x & 63);
}

extern "C" void kernel_launch(void* const* d_in, const int* in_sizes, int n_in,
                              void* d_out, int out_size, void* d_ws, size_t ws_size,
                              hipStream_t stream) {
    (void)in_sizes; (void)n_in;
    const float* x  = (const float*)d_in[0];
    const float* fr = (const float*)d_in[1];
    const float* fi = (const float*)d_in[2];
    float*  out = (float*)d_out;
    float2* G   = (float2*)d_ws;        // BB*CC*512*512 complex = 8 MB

    const size_t fullBytes = (size_t)BB * CC * NGRID * NGRID * sizeof(float2);
    if (ws_size < fullBytes) return;    // diagnostic no-op (ws proven >= 8 MB)

    int out_elems = out_size;
    void* args[] = { (void*)&x, (void*)&fr, (void*)&fi, (void*)&G, (void*)&out, (void*)&out_elems };
    hipError_t err = hipLaunchCooperativeKernel((const void*)nfft29781_fused,
                                                dim3(COOP_BLOCKS), dim3(256),
                                                args, 0, stream);
    if (err != hipSuccess) {
        (void)hipGetLastError();        // clear sticky error, use proven path
        nfft29781_rows_fused<<<BB * CC * NSMALL, 256, 0, stream>>>(fr, fi, G);
        nfft29781_cols<<<BB * CC * NGRID, 256, 0, stream>>>(G);
        int gthreads = BB * CC * MPTS * 8;
        nfft29781_gather_coal<<<(gthreads + 255) / 256, 256, 0, stream>>>(x, G, out, out_size);
    }
}

// Round 9
// 125.282 us; speedup vs baseline: 4.6688x; 4.6688x over previous
//
#include <hip/hip_runtime.h>
#include <math.h>

// ---------------------------------------------------------------------------
// NFFT forward (type-2): f_hat (B,C,256,256 complex) -> samples at M points.
// 3 dispatches (R8 lesson: grid.sync on 8 XCDs costs >>12us/boundary — never
// use cooperative fusion here):
//   rows:  fused deconvolve/pad/fftshift + 512-pt row FFT (256 nonzero rows).
//   cols:  8-column-tiled 512-pt col FFTs — coalesced 64B group reads/writes
//          (R5 lesson applied to cols: strided per-lane loads were 64 lines
//          per wave-load; tiling makes it 8).
//   gather: 8 lanes per (b,point), BOTH channels per group (weights/shfls
//          computed once, two image reads per tap — same line count as R7,
//          ~60% of the VALU work).
// Shift algebra: ifftshift(FFT(fftshift(p)))[(ind+256)%512] == FFT(fftshift(p))[ind&511].
// Output PLANAR: real plane (B,C,M) then imag plane.
// R4 lesson: no forced __launch_bounds__ minima (spill -> dead kernel).
// ---------------------------------------------------------------------------

#define NGRID 512
#define NSMALL 256
#define MW 4
#define BB 2
#define CC 2
#define MPTS 200000
#define PLANE (BB * CC * MPTS)   // imag-plane offset in floats
#define LPAD 513                 // LDS column pitch (512+1, breaks pow2 banking)

// I0(z) asymptotic series, valid z > 8 (our z in [17.7, 18.9])
__device__ __forceinline__ float nfft29781_i0_large(float z) {
    float inv = 1.0f / z;
    float p = 1.0f + inv * (0.125f + inv * (0.0703125f
              + inv * (0.0732421875f + inv * 0.112152099609375f)));
    return expf(z) * rsqrtf(2.0f * (float)M_PI * z) * p;
}

__device__ __forceinline__ int nfft29781_brev9(int v) {
    return (int)(__brev((unsigned)v) >> 23);
}

// 512-pt radix-2 DIT FFT in LDS (input pre-loaded bit-reversed). Rows only.
__device__ __forceinline__ void nfft29781_fft512(float2* s, int tid) {
    #pragma unroll
    for (int st = 0; st < 9; ++st) {
        int half = 1 << st;
        int pos = tid & (half - 1);
        int i0 = ((tid >> st) << (st + 1)) + pos;
        int i1 = i0 + half;
        float ang = -(float)M_PI * (float)pos / (float)half;
        float sn, cs;
        __sincosf(ang, &sn, &cs);
        float2 a = s[i0];
        float2 b = s[i1];
        float2 tw = make_float2(b.x * cs - b.y * sn, b.x * sn + b.y * cs);
        s[i0] = make_float2(a.x + tw.x, a.y + tw.y);
        s[i1] = make_float2(a.x - tw.x, a.y - tw.y);
        __syncthreads();
    }
}

// ---------------------------------------------------------------------------
// Rows (R7-proven body): one block per (img, a1), a1 in [0,256) = f_hat row.
// ---------------------------------------------------------------------------
__global__ __launch_bounds__(256) void nfft29781_rows_fused(const float* __restrict__ fr,
                                                            const float* __restrict__ fi,
                                                            float2* __restrict__ G) {
    __shared__ float2 s[NGRID];
    int tid = threadIdx.x;
    int img = blockIdx.x >> 8;
    int a1  = blockIdx.x & 255;

    const float bcon  = 1.5f * (float)M_PI;
    const float scale = 2.0f * (float)M_PI / (float)NGRID;
    float k1 = (float)(a1 - 128) * scale;
    float p1 = nfft29781_i0_large((float)MW * sqrtf(bcon * bcon - k1 * k1));

    int a2 = tid ^ 128;
    float k2 = (float)(a2 - 128) * scale;
    float p2 = nfft29781_i0_large((float)MW * sqrtf(bcon * bcon - k2 * k2));

    size_t src = ((size_t)img * NSMALL + a1) * NSMALL + a2;
    float invp = 1.0f / (p1 * p2);
    float2 v = make_float2(fr[src] * invp, fi[src] * invp);

    int j2v = (tid < 128) ? tid : tid + 256;        // nonzero staged col
    int j2z = (tid < 128) ? tid + 256 : tid;        // zero staged col
    s[nfft29781_brev9(j2v)] = v;
    s[nfft29781_brev9(j2z)] = make_float2(0.0f, 0.0f);
    __syncthreads();

    nfft29781_fft512(s, tid);

    int j1 = (a1 < 128) ? a1 + 384 : a1 - 128;      // staged row (fftshift fold)
    size_t base = ((size_t)img * NGRID + j1) * NGRID;
    G[base + tid]       = s[tid];
    G[base + tid + 256] = s[tid + 256];
}

// ---------------------------------------------------------------------------
// Cols, tiled: one block per (img, 8-column group); 256 blocks. Flattened
// (row, col-in-tile) indexing -> each aligned 8-lane group reads/writes one
// contiguous 64B segment. 8 concurrent FFTs in LDS: c = tid&7 owns a column,
// w = tid>>3 in [0,32) does 8 butterflies (bf = w + 32k) per stage.
// Middle rows [128,384) are structurally zero (never written by rows_fused).
// ---------------------------------------------------------------------------
__global__ __launch_bounds__(256) void nfft29781_cols_tiled(float2* __restrict__ G) {
    __shared__ float2 s[8 * LPAD];                  // 32.8 KB
    int tid  = threadIdx.x;
    int img  = blockIdx.x >> 6;
    int col0 = (blockIdx.x & 63) << 3;
    float2* Gimg = G + (size_t)img * NGRID * NGRID;

    // load 256 nonzero rows x 8 cols, bit-reversed into LDS
    #pragma unroll
    for (int it = 0; it < 8; ++it) {
        int e  = it * 256 + tid;                    // 0..2047
        int cp = e & 7;
        int q  = e >> 3;                            // 0..255
        int r  = (q < 128) ? q : q + 256;           // nonzero row
        s[cp * LPAD + nfft29781_brev9(r)] = Gimg[(size_t)r * NGRID + col0 + cp];
    }
    // zero the 256 middle rows
    #pragma unroll
    for (int it = 0; it < 8; ++it) {
        int e  = it * 256 + tid;
        int cp = e & 7;
        int q  = e >> 3;
        s[cp * LPAD + nfft29781_brev9(q + 128)] = make_float2(0.0f, 0.0f);
    }
    __syncthreads();

    // 8 column-FFTs in parallel
    int c = tid & 7;
    int w = tid >> 3;                               // 0..31
    float2* sc = s + c * LPAD;
    for (int st = 0; st < 9; ++st) {
        int half = 1 << st;
        #pragma unroll
        for (int k = 0; k < 8; ++k) {
            int bf  = w + (k << 5);                 // 0..255
            int pos = bf & (half - 1);
            int i0  = ((bf >> st) << (st + 1)) + pos;
            int i1  = i0 + half;
            float ang = -(float)M_PI * (float)pos / (float)half;
            float sn, cs;
            __sincosf(ang, &sn, &cs);
            float2 a = sc[i0];
            float2 b = sc[i1];
            float2 tw = make_float2(b.x * cs - b.y * sn, b.x * sn + b.y * cs);
            sc[i0] = make_float2(a.x + tw.x, a.y + tw.y);
            sc[i1] = make_float2(a.x - tw.x, a.y - tw.y);
        }
        __syncthreads();
    }

    // write back all 512 rows x 8 cols (coalesced 64B per 8-lane group)
    #pragma unroll
    for (int it = 0; it < 16; ++it) {
        int e  = it * 256 + tid;                    // 0..4095
        int cp = e & 7;
        int r  = e >> 3;                            // 0..511
        Gimg[(size_t)r * NGRID + col0 + cp] = s[cp * LPAD + r];
    }
}

// ---------------------------------------------------------------------------
// Gather, channel-merged: 8 lanes per (b, point); each group computes the
// Kaiser-Bessel weights ONCE and reads both channel images' 64B row chunks.
// Lane j owns column-tap j. w0[i] broadcast via __shfl; 3-stage __shfl_xor
// sums the 8 taps for all 4 accumulators; lane 0 writes planar out.
// Weight sequence bit-matches reference ceil(x*n)-m.
// ---------------------------------------------------------------------------
__global__ __launch_bounds__(256) void nfft29781_gather2(const float* __restrict__ x,
                                                         const float2* __restrict__ G,
                                                         float* __restrict__ out,
                                                         int out_elems) {
    int t  = blockIdx.x * blockDim.x + threadIdx.x;
    int j  = t & 7;                  // my column tap
    int pp = t >> 3;                 // (b, point) id — shared by 8 group lanes
    if (pp >= BB * MPTS) return;
    int b  = (pp >= MPTS) ? 1 : 0;
    int pt = pp - b * MPTS;

    float u0 = x[(size_t)pp * 2 + 0] * (float)NGRID;   // broadcast within group
    float u1 = x[(size_t)pp * 2 + 1] * (float)NGRID;

    float c0 = ceilf(u0), c1 = ceilf(u1);
    int base0 = (int)c0 - MW;
    int base1 = (int)c1 - MW;
    float d0 = c0 - u0, d1 = c1 - u1;

    const float bw = 1.5f * (float)M_PI;
    const float invpi = 1.0f / (float)M_PI;
    float w0m, w1m;   // my dim-0 / dim-1 tap-j weights
    {
        float nk = (float)(MW - j) - d0;
        float tt = (float)(MW * MW) - nk * nk;
        w0m = 0.0f;
        if (tt > 0.0f) { float a = sqrtf(tt); float e = expf(bw * a);
                         w0m = (e - 1.0f / e) * 0.5f * invpi / a; }
        nk = (float)(MW - j) - d1;
        tt = (float)(MW * MW) - nk * nk;
        w1m = 0.0f;
        if (tt > 0.0f) { float a = sqrtf(tt); float e = expf(bw * a);
                         w1m = (e - 1.0f / e) * 0.5f * invpi / a; }
    }

    const float2* Gi0 = G + (size_t)(b * CC) * NGRID * NGRID;   // channel 0
    const float2* Gi1 = Gi0 + (size_t)NGRID * NGRID;            // channel 1
    int cix = (base1 + j) & (NGRID - 1);
    int lanebase = (threadIdx.x & 63) & ~7;

    float a0x = 0.0f, a0y = 0.0f, a1x = 0.0f, a1y = 0.0f;
    #pragma unroll
    for (int i = 0; i < 8; ++i) {
        float w0i = __shfl(w0m, lanebase + i, 64);   // row-i weight
        int off = (((base0 + i) & (NGRID - 1)) << 9) + cix;
        float2 g0 = Gi0[off];
        float2 g1 = Gi1[off];
        a0x += w0i * g0.x;  a0y += w0i * g0.y;
        a1x += w0i * g1.x;  a1y += w0i * g1.y;
    }
    a0x *= w1m;  a0y *= w1m;  a1x *= w1m;  a1y *= w1m;

    #pragma unroll
    for (int msk = 1; msk < 8; msk <<= 1) {          // sum the 8 column taps
        a0x += __shfl_xor(a0x, msk, 64);
        a0y += __shfl_xor(a0y, msk, 64);
        a1x += __shfl_xor(a1x, msk, 64);
        a1y += __shfl_xor(a1y, msk, 64);
    }

    if (j == 0) {
        size_t o0 = (size_t)(b * CC) * MPTS + pt;    // channel 0
        size_t o1 = o0 + MPTS;                       // channel 1
        if (o0 < (size_t)out_elems)         out[o0]         = a0x;
        if (PLANE + o0 < (size_t)out_elems) out[PLANE + o0] = a0y;
        if (o1 < (size_t)out_elems)         out[o1]         = a1x;
        if (PLANE + o1 < (size_t)out_elems) out[PLANE + o1] = a1y;
    }
}

extern "C" void kernel_launch(void* const* d_in, const int* in_sizes, int n_in,
                              void* d_out, int out_size, void* d_ws, size_t ws_size,
                              hipStream_t stream) {
    (void)in_sizes; (void)n_in;
    const float* x  = (const float*)d_in[0];
    const float* fr = (const float*)d_in[1];
    const float* fi = (const float*)d_in[2];
    float*  out = (float*)d_out;
    float2* G   = (float2*)d_ws;        // BB*CC*512*512 complex = 8 MB

    const size_t fullBytes = (size_t)BB * CC * NGRID * NGRID * sizeof(float2);
    if (ws_size < fullBytes) return;    // diagnostic no-op (ws proven >= 8 MB)

    nfft29781_rows_fused<<<BB * CC * NSMALL, 256, 0, stream>>>(fr, fi, G);
    nfft29781_cols_tiled<<<BB * CC * (NGRID / 8), 256, 0, stream>>>(G);
    int gthreads = BB * MPTS * 8;       // 8 lanes per (b,point), both channels
    nfft29781_gather2<<<(gthreads + 255) / 256, 256, 0, stream>>>(x, G, out, out_size);
}

// Round 10
// 99.195 us; speedup vs baseline: 5.8966x; 1.2630x over previous
//
#include <hip/hip_runtime.h>
#include <math.h>

// ---------------------------------------------------------------------------
// NFFT forward (type-2): f_hat (B,C,256,256 complex) -> samples at M points.
// 3 dispatches (R8: cooperative grid.sync is catastrophically slow on 8 XCDs):
//   rows: channel-merged fused deconvolve/pad/fftshift + 512-pt row FFT.
//         Both channels of one b-image ride in a float4 (re0,im0,re1,im1),
//         sharing twiddles. Writes fp32 G32 rows [0,128)u[384,512) only.
//   cols: 4-column tiles, float4 butterflies, zeros injected for middle rows;
//         output packed to bf16x4 (8 B per (row,col), both channels) into the
//         never-written middle-row region of G32 (exact 2 MB/image fit) so
//         workspace stays within the proven 8 MB.
//   gather: 8 lanes per (b,point); per row-tap ONE 8B load/lane yields both
//         channels (R9 was 2x 8B into distinct images). Halves loads, lines,
//         and footprint. fp32 accumulation; single bf16 rounding layer.
// Shift algebra: ifftshift(FFT(fftshift(p)))[(ind+256)%512] == FFT(fftshift(p))[ind&511].
// Output PLANAR: real plane (B,C,M) then imag plane.
// R4: no forced __launch_bounds__ minima (spill -> dead kernel).
// R5: coalesce scattered gathers. R7: ~12-15us per dispatch boundary.
// ---------------------------------------------------------------------------

#define NGRID 512
#define NSMALL 256
#define MW 4
#define BB 2
#define CC 2
#define MPTS 200000
#define PLANE (BB * CC * MPTS)   // imag-plane offset in floats
#define LPAD4 513                // LDS pitch in float4 (breaks pow2 banking)
#define IMG4 (NGRID * NGRID)     // float4 elems per b-image in G32
// G16 (uint2 units): image b's packed grid lives in G32's middle rows
#define G16OFF(b) ((size_t)(b) * 524288 + 131072)

// I0(z) asymptotic series, valid z > 8 (our z in [17.7, 18.9])
__device__ __forceinline__ float nfft29781_i0_large(float z) {
    float inv = 1.0f / z;
    float p = 1.0f + inv * (0.125f + inv * (0.0703125f
              + inv * (0.0732421875f + inv * 0.112152099609375f)));
    return expf(z) * rsqrtf(2.0f * (float)M_PI * z) * p;
}

__device__ __forceinline__ int nfft29781_brev9(int v) {
    return (int)(__brev((unsigned)v) >> 23);
}

__device__ __forceinline__ unsigned nfft29781_bf16pack(float a, float b) {
    unsigned ua = __float_as_uint(a);
    ua += 0x7FFFu + ((ua >> 16) & 1u);           // RNE
    unsigned ub = __float_as_uint(b);
    ub += 0x7FFFu + ((ub >> 16) & 1u);
    return (ua >> 16) | (ub & 0xFFFF0000u);
}

// 512-pt radix-2 DIT FFT on complex PAIRS (float4 = two complexes), in LDS.
__device__ __forceinline__ void nfft29781_fft512_c2(float4* s, int tid) {
    #pragma unroll
    for (int st = 0; st < 9; ++st) {
        int half = 1 << st;
        int pos = tid & (half - 1);
        int i0 = ((tid >> st) << (st + 1)) + pos;
        int i1 = i0 + half;
        float ang = -(float)M_PI * (float)pos / (float)half;
        float sn, cs;
        __sincosf(ang, &sn, &cs);
        float4 a = s[i0];
        float4 b = s[i1];
        float4 tw;
        tw.x = b.x * cs - b.y * sn;  tw.y = b.x * sn + b.y * cs;
        tw.z = b.z * cs - b.w * sn;  tw.w = b.z * sn + b.w * cs;
        s[i0] = make_float4(a.x + tw.x, a.y + tw.y, a.z + tw.z, a.w + tw.w);
        s[i1] = make_float4(a.x - tw.x, a.y - tw.y, a.z - tw.z, a.w - tw.w);
        __syncthreads();
    }
}

// ---------------------------------------------------------------------------
// Rows: one block per (b, a1), a1 in [0,256) = f_hat row; both channels.
// Staged row j1 = (a1<128)? a1+384 : a1-128 (always outside [128,384)).
// ---------------------------------------------------------------------------
__global__ __launch_bounds__(256) void nfft29781_rows2(const float* __restrict__ fr,
                                                       const float* __restrict__ fi,
                                                       float4* __restrict__ G32) {
    __shared__ float4 s[NGRID];
    int tid = threadIdx.x;
    int b   = blockIdx.x >> 8;
    int a1  = blockIdx.x & 255;

    const float bcon  = 1.5f * (float)M_PI;
    const float scale = 2.0f * (float)M_PI / (float)NGRID;
    float k1 = (float)(a1 - 128) * scale;
    float p1 = nfft29781_i0_large((float)MW * sqrtf(bcon * bcon - k1 * k1));

    int a2 = tid ^ 128;
    float k2 = (float)(a2 - 128) * scale;
    float p2 = nfft29781_i0_large((float)MW * sqrtf(bcon * bcon - k2 * k2));
    float invp = 1.0f / (p1 * p2);

    size_t s0 = ((size_t)(b * CC + 0) * NSMALL + a1) * NSMALL + a2;
    size_t s1 = ((size_t)(b * CC + 1) * NSMALL + a1) * NSMALL + a2;
    float4 v = make_float4(fr[s0] * invp, fi[s0] * invp,
                           fr[s1] * invp, fi[s1] * invp);

    int j2v = (tid < 128) ? tid : tid + 256;        // nonzero staged col
    int j2z = (tid < 128) ? tid + 256 : tid;        // zero staged col
    s[nfft29781_brev9(j2v)] = v;
    s[nfft29781_brev9(j2z)] = make_float4(0.0f, 0.0f, 0.0f, 0.0f);
    __syncthreads();

    nfft29781_fft512_c2(s, tid);

    int j1 = (a1 < 128) ? a1 + 384 : a1 - 128;      // staged row (fftshift fold)
    float4* Gb = G32 + (size_t)b * IMG4 + (size_t)j1 * NGRID;
    Gb[tid]       = s[tid];
    Gb[tid + 256] = s[tid + 256];
}

// ---------------------------------------------------------------------------
// Cols: one block per (b, 4-col group); 256 blocks. Reads the 256 nonzero
// rows (fp32 float4), injects zeros for middle rows, 4 concurrent FFTs,
// packs result to bf16x4 into G32's middle-row region (disjoint from reads).
// ---------------------------------------------------------------------------
__global__ __launch_bounds__(256) void nfft29781_cols2(float4* __restrict__ G32) {
    __shared__ float4 s[4 * LPAD4];                 // 32.8 KB
    int tid  = threadIdx.x;
    int b    = blockIdx.x >> 7;
    int col0 = (blockIdx.x & 127) << 2;
    const float4* Gb = G32 + (size_t)b * IMG4;

    // load 256 nonzero rows x 4 cols (each aligned 4-lane group: 64B contig)
    #pragma unroll
    for (int it = 0; it < 4; ++it) {
        int e  = it * 256 + tid;                    // 0..1023
        int cp = e & 3;
        int q  = e >> 2;                            // 0..255
        int r  = (q < 128) ? q : q + 256;           // nonzero row
        s[cp * LPAD4 + nfft29781_brev9(r)] = Gb[(size_t)r * NGRID + col0 + cp];
    }
    // zero the 256 middle rows
    #pragma unroll
    for (int it = 0; it < 4; ++it) {
        int e  = it * 256 + tid;
        int cp = e & 3;
        int q  = e >> 2;
        s[cp * LPAD4 + nfft29781_brev9(q + 128)] = make_float4(0.0f, 0.0f, 0.0f, 0.0f);
    }
    __syncthreads();

    // 4 column-FFTs in parallel: c owns a column, w does 4 butterflies/stage
    int c = tid & 3;
    int w = tid >> 2;                               // 0..63
    float4* sc = s + c * LPAD4;
    for (int st = 0; st < 9; ++st) {
        int half = 1 << st;
        #pragma unroll
        for (int k = 0; k < 4; ++k) {
            int bf  = w + (k << 6);                 // 0..255
            int pos = bf & (half - 1);
            int i0  = ((bf >> st) << (st + 1)) + pos;
            int i1  = i0 + half;
            float ang = -(float)M_PI * (float)pos / (float)half;
            float sn, cs;
            __sincosf(ang, &sn, &cs);
            float4 a = sc[i0];
            float4 bb = sc[i1];
            float4 tw;
            tw.x = bb.x * cs - bb.y * sn;  tw.y = bb.x * sn + bb.y * cs;
            tw.z = bb.z * cs - bb.w * sn;  tw.w = bb.z * sn + bb.w * cs;
            sc[i0] = make_float4(a.x + tw.x, a.y + tw.y, a.z + tw.z, a.w + tw.w);
            sc[i1] = make_float4(a.x - tw.x, a.y - tw.y, a.z - tw.z, a.w - tw.w);
        }
        __syncthreads();
    }

    // pack + write all 512 rows x 4 cols into the middle-row region (uint2)
    uint2* G16 = (uint2*)G32 + G16OFF(b);
    #pragma unroll
    for (int it = 0; it < 8; ++it) {
        int e  = it * 256 + tid;                    // 0..2047
        int cp = e & 3;
        int r  = e >> 2;                            // 0..511
        float4 v = s[cp * LPAD4 + r];
        uint2 pk;
        pk.x = nfft29781_bf16pack(v.x, v.y);        // ch0 re|im
        pk.y = nfft29781_bf16pack(v.z, v.w);        // ch1 re|im
        G16[(size_t)r * NGRID + col0 + cp] = pk;
    }
}

// ---------------------------------------------------------------------------
// Gather: 8 lanes per (b,point); lane j owns column-tap j. Per row-tap ONE
// 8B load/lane -> both channels (bf16x4). Weights computed once per group,
// w0[i] broadcast via __shfl; 3-stage __shfl_xor sums; lane 0 writes planar.
// Weight sequence bit-matches reference ceil(x*n)-m.
// ---------------------------------------------------------------------------
__global__ __launch_bounds__(256) void nfft29781_gather_bf16(const float* __restrict__ x,
                                                             const uint2* __restrict__ G16base,
                                                             float* __restrict__ out,
                                                             int out_elems) {
    int t  = blockIdx.x * blockDim.x + threadIdx.x;
    int j  = t & 7;                  // my column tap
    int pp = t >> 3;                 // (b, point) id — shared by 8 group lanes
    if (pp >= BB * MPTS) return;
    int b  = (pp >= MPTS) ? 1 : 0;
    int pt = pp - b * MPTS;

    float u0 = x[(size_t)pp * 2 + 0] * (float)NGRID;   // broadcast within group
    float u1 = x[(size_t)pp * 2 + 1] * (float)NGRID;

    float c0 = ceilf(u0), c1 = ceilf(u1);
    int base0 = (int)c0 - MW;
    int base1 = (int)c1 - MW;
    float d0 = c0 - u0, d1 = c1 - u1;

    const float bw = 1.5f * (float)M_PI;
    const float invpi = 1.0f / (float)M_PI;
    float w0m, w1m;   // my dim-0 / dim-1 tap-j weights
    {
        float nk = (float)(MW - j) - d0;
        float tt = (float)(MW * MW) - nk * nk;
        w0m = 0.0f;
        if (tt > 0.0f) { float a = sqrtf(tt); float e = expf(bw * a);
                         w0m = (e - 1.0f / e) * 0.5f * invpi / a; }
        nk = (float)(MW - j) - d1;
        tt = (float)(MW * MW) - nk * nk;
        w1m = 0.0f;
        if (tt > 0.0f) { float a = sqrtf(tt); float e = expf(bw * a);
                         w1m = (e - 1.0f / e) * 0.5f * invpi / a; }
    }

    const uint2* Gi = G16base + G16OFF(b);
    int cix = (base1 + j) & (NGRID - 1);
    int lanebase = (threadIdx.x & 63) & ~7;

    float a0x = 0.0f, a0y = 0.0f, a1x = 0.0f, a1y = 0.0f;
    #pragma unroll
    for (int i = 0; i < 8; ++i) {
        float w0i = __shfl(w0m, lanebase + i, 64);   // row-i weight
        uint2 g = Gi[(size_t)(((base0 + i) & (NGRID - 1)) << 9) + cix];
        float g0x = __uint_as_float(g.x << 16);
        float g0y = __uint_as_float(g.x & 0xFFFF0000u);
        float g1x = __uint_as_float(g.y << 16);
        float g1y = __uint_as_float(g.y & 0xFFFF0000u);
        a0x += w0i * g0x;  a0y += w0i * g0y;
        a1x += w0i * g1x;  a1y += w0i * g1y;
    }
    a0x *= w1m;  a0y *= w1m;  a1x *= w1m;  a1y *= w1m;

    #pragma unroll
    for (int msk = 1; msk < 8; msk <<= 1) {          // sum the 8 column taps
        a0x += __shfl_xor(a0x, msk, 64);
        a0y += __shfl_xor(a0y, msk, 64);
        a1x += __shfl_xor(a1x, msk, 64);
        a1y += __shfl_xor(a1y, msk, 64);
    }

    if (j == 0) {
        size_t o0 = (size_t)(b * CC) * MPTS + pt;    // channel 0
        size_t o1 = o0 + MPTS;                       // channel 1
        if (o0 < (size_t)out_elems)         out[o0]         = a0x;
        if (PLANE + o0 < (size_t)out_elems) out[PLANE + o0] = a0y;
        if (o1 < (size_t)out_elems)         out[o1]         = a1x;
        if (PLANE + o1 < (size_t)out_elems) out[PLANE + o1] = a1y;
    }
}

extern "C" void kernel_launch(void* const* d_in, const int* in_sizes, int n_in,
                              void* d_out, int out_size, void* d_ws, size_t ws_size,
                              hipStream_t stream) {
    (void)in_sizes; (void)n_in;
    const float* x  = (const float*)d_in[0];
    const float* fr = (const float*)d_in[1];
    const float* fi = (const float*)d_in[2];
    float*  out = (float*)d_out;
    float4* G32 = (float4*)d_ws;        // BB * 512*512 float4 = 8 MB

    const size_t fullBytes = (size_t)BB * IMG4 * sizeof(float4);
    if (ws_size < fullBytes) return;    // diagnostic no-op (ws proven >= 8 MB)

    nfft29781_rows2<<<BB * NSMALL, 256, 0, stream>>>(fr, fi, G32);
    nfft29781_cols2<<<BB * (NGRID / 4), 256, 0, stream>>>(G32);
    int gthreads = BB * MPTS * 8;       // 8 lanes per (b,point), both channels
    nfft29781_gather_bf16<<<(gthreads + 255) / 256, 256, 0, stream>>>(
        x, (const uint2*)d_ws, out, out_size);
}